// Round 2
// baseline (135.025 us; speedup 1.0000x reference)
//
#include <hip/hip_runtime.h>
#include <hip/hip_bf16.h>

typedef unsigned short ushort_t;
typedef __attribute__((ext_vector_type(8))) short short8;   // 8 bf16 (4 VGPRs)
typedef __attribute__((ext_vector_type(4))) short short4v;  // 4 bf16 (2 VGPRs)
typedef __attribute__((ext_vector_type(4))) float f32x4;    // 4 fp32 acc

__device__ __forceinline__ float bf2f(ushort_t u) {
    unsigned int x = ((unsigned int)u) << 16;
    float f; __builtin_memcpy(&f, &x, 4); return f;
}
__device__ __forceinline__ ushort_t f2bf(float f) {
    __hip_bfloat16 h = __float2bfloat16(f);
    ushort_t u; __builtin_memcpy(&u, &h, 2); return u;
}
__device__ __forceinline__ unsigned packbf2(float a, float b) {
    return (unsigned)f2bf(a) | ((unsigned)f2bf(b) << 16);
}

constexpr int E  = 1024;
constexpr int Hd = 64;
constexpr int S  = 2048;
constexpr int ROWS = 8 * 2048;   // 16384
constexpr int NTOT = 192;
constexpr int LST  = 88;         // proj LDS row stride
constexpr int LSTA = 72;         // attn LDS row stride (144B rows; bank-checked)

// ---------------------------------------------------------------------------
// prep: WT[192][1024] bf16, rows 0-63 = Wq^T, 64-127 = Wk^T, 128-191 = Wv^T
__global__ __launch_bounds__(256)
void prep_wt(const float* __restrict__ Wk, const float* __restrict__ Wq,
             const float* __restrict__ Wv, ushort_t* __restrict__ WT)
{
    int idx = blockIdx.x * 256 + threadIdx.x;
    int n = idx >> 10;
    int kk = idx & 1023;
    const float* W = (n < 64) ? Wq : ((n < 128) ? Wk : Wv);
    int h = n & 63;
    WT[idx] = f2bf(W[kk * Hd + h]);
}

// ---------------------------------------------------------------------------
// Projection v9: 2-deep x prefetch (HBM ~900cyc now covered by ~2 compute
// phases) + single-barrier double-buffered XS (write buf; sync; prefetch;
// compute). Manual 2-body unroll keeps buffers/regs statically indexed.
__global__ __launch_bounds__(256)
void proj_v7(const float* __restrict__ x, const ushort_t* __restrict__ WT,
             ushort_t* __restrict__ qo, ushort_t* __restrict__ ko,
             ushort_t* __restrict__ vTo)
{
    __shared__ alignas(16) ushort_t XS0[32][LST];
    __shared__ alignas(16) ushort_t XS1[32][LST];

    const int t    = threadIdx.x;
    const int w    = t >> 6;
    const int lane = t & 63;
    const int m    = lane & 15;
    const int g    = lane >> 4;
    const int rb   = blockIdx.x * 32;

    f32x4 accq[2], acck[2], accv[2];
    #pragma unroll
    for (int j = 0; j < 2; ++j) {
        accq[j] = (f32x4){0.f, 0.f, 0.f, 0.f};
        acck[j] = (f32x4){0.f, 0.f, 0.f, 0.f};
        accv[j] = (f32x4){0.f, 0.f, 0.f, 0.f};
    }

    const float* xptr = x + (size_t)(rb + (t >> 3)) * E + (t & 7) * 8;
    const ushort_t* wqp = WT + (size_t)(w * 16 + m) * E + g * 8;
    const ushort_t* wkp = wqp + (size_t)64 * E;
    const ushort_t* wvp = wqp + (size_t)128 * E;

    const int sr = t >> 3, sc = (t & 7) * 8;

    // x prefetch, 2-deep: A holds even-c data, B holds odd-c data.
    float4 xA0 = *(const float4*)xptr;
    float4 xA1 = *(const float4*)(xptr + 4);
    float4 xB0 = *(const float4*)(xptr + 64);
    float4 xB1 = *(const float4*)(xptr + 64 + 4);

    // weights, alternating sets (wA = even body, wB = odd body)
    short8 wAq[2], wAk[2], wAv[2], wBq[2], wBk[2], wBv[2];
    #pragma unroll
    for (int kt = 0; kt < 2; ++kt) {
        wAq[kt] = *(const short8*)(wqp + kt * 32);
        wAk[kt] = *(const short8*)(wkp + kt * 32);
        wAv[kt] = *(const short8*)(wvp + kt * 32);
    }

    #pragma unroll 1
    for (int cc = 0; cc < 16; cc += 2) {
        // ---------------- even body: c = cc, buffer XS0, weights wA
        {
            uint4 sv;
            sv.x = packbf2(xA0.x, xA0.y);
            sv.y = packbf2(xA0.z, xA0.w);
            sv.z = packbf2(xA1.x, xA1.y);
            sv.w = packbf2(xA1.z, xA1.w);
            *(uint4*)&XS0[sr][sc] = sv;
        }
        __syncthreads();
        if (cc + 2 < 16) {
            const int k0 = (cc + 2) * 64;
            xA0 = *(const float4*)(xptr + k0);
            xA1 = *(const float4*)(xptr + k0 + 4);
        }
        {   // weights for c = cc+1 (always valid)
            const int k0 = (cc + 1) * 64;
            #pragma unroll
            for (int kt = 0; kt < 2; ++kt) {
                wBq[kt] = *(const short8*)(wqp + k0 + kt * 32);
                wBk[kt] = *(const short8*)(wkp + k0 + kt * 32);
                wBv[kt] = *(const short8*)(wvp + k0 + kt * 32);
            }
        }
        #pragma unroll
        for (int kt = 0; kt < 2; ++kt) {
            short8 a0 = *(const short8*)&XS0[m][kt * 32 + g * 8];
            short8 a1 = *(const short8*)&XS0[16 + m][kt * 32 + g * 8];
            accq[0] = __builtin_amdgcn_mfma_f32_16x16x32_bf16(a0, wAq[kt], accq[0], 0, 0, 0);
            accq[1] = __builtin_amdgcn_mfma_f32_16x16x32_bf16(a1, wAq[kt], accq[1], 0, 0, 0);
            acck[0] = __builtin_amdgcn_mfma_f32_16x16x32_bf16(a0, wAk[kt], acck[0], 0, 0, 0);
            acck[1] = __builtin_amdgcn_mfma_f32_16x16x32_bf16(a1, wAk[kt], acck[1], 0, 0, 0);
            accv[0] = __builtin_amdgcn_mfma_f32_16x16x32_bf16(wAv[kt], a0, accv[0], 0, 0, 0);
            accv[1] = __builtin_amdgcn_mfma_f32_16x16x32_bf16(wAv[kt], a1, accv[1], 0, 0, 0);
        }

        // ---------------- odd body: c = cc+1, buffer XS1, weights wB
        {
            uint4 sv;
            sv.x = packbf2(xB0.x, xB0.y);
            sv.y = packbf2(xB0.z, xB0.w);
            sv.z = packbf2(xB1.x, xB1.y);
            sv.w = packbf2(xB1.z, xB1.w);
            *(uint4*)&XS1[sr][sc] = sv;
        }
        __syncthreads();
        if (cc + 3 < 16) {
            const int k0 = (cc + 3) * 64;
            xB0 = *(const float4*)(xptr + k0);
            xB1 = *(const float4*)(xptr + k0 + 4);
        }
        if (cc + 2 < 16) {
            const int k0 = (cc + 2) * 64;
            #pragma unroll
            for (int kt = 0; kt < 2; ++kt) {
                wAq[kt] = *(const short8*)(wqp + k0 + kt * 32);
                wAk[kt] = *(const short8*)(wkp + k0 + kt * 32);
                wAv[kt] = *(const short8*)(wvp + k0 + kt * 32);
            }
        }
        #pragma unroll
        for (int kt = 0; kt < 2; ++kt) {
            short8 a0 = *(const short8*)&XS1[m][kt * 32 + g * 8];
            short8 a1 = *(const short8*)&XS1[16 + m][kt * 32 + g * 8];
            accq[0] = __builtin_amdgcn_mfma_f32_16x16x32_bf16(a0, wBq[kt], accq[0], 0, 0, 0);
            accq[1] = __builtin_amdgcn_mfma_f32_16x16x32_bf16(a1, wBq[kt], accq[1], 0, 0, 0);
            acck[0] = __builtin_amdgcn_mfma_f32_16x16x32_bf16(a0, wBk[kt], acck[0], 0, 0, 0);
            acck[1] = __builtin_amdgcn_mfma_f32_16x16x32_bf16(a1, wBk[kt], acck[1], 0, 0, 0);
            accv[0] = __builtin_amdgcn_mfma_f32_16x16x32_bf16(wBv[kt], a0, accv[0], 0, 0, 0);
            accv[1] = __builtin_amdgcn_mfma_f32_16x16x32_bf16(wBv[kt], a1, accv[1], 0, 0, 0);
        }
    }

    const int col   = w * 16 + m;
    const int batch = rb >> 11;
    const int seq0  = rb & (S - 1);
    #pragma unroll
    for (int mt = 0; mt < 2; ++mt) {
        const int orow = rb + mt * 16 + g * 4;
        #pragma unroll
        for (int r = 0; r < 4; ++r) {
            qo[(size_t)(orow + r) * Hd + col] = f2bf(accq[mt][r] * 0.125f);
            ko[(size_t)(orow + r) * Hd + col] = f2bf(acck[mt][r]);
        }
    }
    #pragma unroll
    for (int ns = 0; ns < 2; ++ns)
        #pragma unroll
        for (int r = 0; r < 4; ++r) {
            const int h = w * 16 + g * 4 + r;
            vTo[(size_t)batch * Hd * S + (size_t)h * S + seq0 + ns * 16 + m]
                = f2bf(accv[ns][r]);
        }
}

// ---------------------------------------------------------------------------
// Attention v11 — swapped-operand QK^T + lane-local PV (R0) and now
// single-barrier double-buffered KS/VTS: per key-tile iter:
//   ds_write buf[bit]; __syncthreads(); prefetch next tile; compute buf[bit].
// Safety: readers of buf[bit] at iter n-2 are separated from the writers at
// iter n by the barrier of iter n-1. Barriers/iter 2->1; LDS pad 88->72 so
// the double buffer (36.9 KB) keeps 4 blocks/CU.
__global__ __launch_bounds__(256)
void attn_part(const ushort_t* __restrict__ q, const ushort_t* __restrict__ k,
               const ushort_t* __restrict__ vT,
               float* __restrict__ lp, ushort_t* __restrict__ op)
{
    const int bi     = blockIdx.x;
    const int parity = bi & 3;
    const int pr     = bi >> 2;
    const int batch  = pr & 7;
    const int tile   = 31 - (pr >> 3);   // longest-first
    const int qs0    = tile * 64;
    const int sidx   = (batch * 32 + tile) * 4 + parity;

    const ushort_t* kb  = k  + (size_t)batch * S * Hd;
    const ushort_t* vTb = vT + (size_t)batch * Hd * S;

    const int t    = threadIdx.x;
    const int w    = t >> 6;
    const int lane = t & 63;
    const int m    = lane & 15;
    const int g    = lane >> 4;

    __shared__ alignas(16) ushort_t KS [2][64][LSTA];
    __shared__ alignas(16) ushort_t VTS[2][64][LSTA];

    const ushort_t* qrow = q + (size_t)(batch * S + qs0 + w * 16 + m) * Hd;
    short8 qf0 = *(const short8*)(qrow + g * 8);
    short8 qf1 = *(const short8*)(qrow + 32 + g * 8);

    f32x4 o[4];
    #pragma unroll
    for (int j = 0; j < 4; ++j) o[j] = (f32x4){0.f, 0.f, 0.f, 0.f};
    float lrun = 0.f;
    const int qr = w * 16 + m;   // q row within the 64-row block (mask)

    const int r1 = t >> 3, c16 = (t & 7) * 8;
    uint4 pk0, pk1, pv0, pv1;

    int c = parity;
    if (c <= tile) {
        const int key0 = c * 64;
        const ushort_t* kt_base = kb + (size_t)key0 * Hd;   // 8 KB flat
        pk0 = *(const uint4*)(kt_base + t * 8);
        pk1 = *(const uint4*)(kt_base + (t + 256) * 8);
        pv0 = *(const uint4*)(vTb + (size_t)r1 * S + key0 + c16);
        pv1 = *(const uint4*)(vTb + (size_t)(r1 + 32) * S + key0 + c16);
    }

    int bit = 0;
    for (; c <= tile; c += 4, bit ^= 1) {
        // ---- stage current tile into buf[bit], then the single barrier
        *(uint4*)&KS [bit][r1][c16]       = pk0;
        *(uint4*)&KS [bit][r1 + 32][c16]  = pk1;
        *(uint4*)&VTS[bit][r1][c16]       = pv0;
        *(uint4*)&VTS[bit][r1 + 32][c16]  = pv1;
        __syncthreads();

        if (c + 4 <= tile) {
            const int key0n = (c + 4) * 64;
            const ushort_t* kt_base = kb + (size_t)key0n * Hd;
            pk0 = *(const uint4*)(kt_base + t * 8);
            pk1 = *(const uint4*)(kt_base + (t + 256) * 8);
            pv0 = *(const uint4*)(vTb + (size_t)r1 * S + key0n + c16);
            pv1 = *(const uint4*)(vTb + (size_t)(r1 + 32) * S + key0n + c16);
        }

        // ---- S^T = K Q^T: sacc[nt][r] = S[q = w*16+m][key = nt*16+g*4+r]
        f32x4 sacc[4];
        #pragma unroll
        for (int j = 0; j < 4; ++j) sacc[j] = (f32x4){0.f, 0.f, 0.f, 0.f};
        #pragma unroll
        for (int nt = 0; nt < 4; ++nt) {
            short8 b0 = *(const short8*)&KS[bit][nt * 16 + m][g * 8];
            short8 b1 = *(const short8*)&KS[bit][nt * 16 + m][32 + g * 8];
            sacc[nt] = __builtin_amdgcn_mfma_f32_16x16x32_bf16(b0, qf0, sacc[nt], 0, 0, 0);
            sacc[nt] = __builtin_amdgcn_mfma_f32_16x16x32_bf16(b1, qf1, sacc[nt], 0, 0, 0);
        }

        // ---- P = exp(S), causal mask on the diagonal tile (no max shift)
        if (c == tile) {
            #pragma unroll
            for (int nt = 0; nt < 4; ++nt)
                #pragma unroll
                for (int r = 0; r < 4; ++r) {
                    const int keyl = nt * 16 + g * 4 + r;
                    sacc[nt][r] = (keyl > qr) ? 0.f : __expf(sacc[nt][r]);
                }
        } else {
            #pragma unroll
            for (int nt = 0; nt < 4; ++nt)
                #pragma unroll
                for (int r = 0; r < 4; ++r)
                    sacc[nt][r] = __expf(sacc[nt][r]);
        }

        // ---- per-lane l accumulation (q fixed = m per lane)
        #pragma unroll
        for (int nt = 0; nt < 4; ++nt)
            lrun += (sacc[nt][0] + sacc[nt][1]) + (sacc[nt][2] + sacc[nt][3]);

        // ---- pack P to bf16 (pairs -> v_cvt_pk_bf16_f32)
        unsigned pw0[4], pw1[4];
        #pragma unroll
        for (int s = 0; s < 4; ++s) {
            pw0[s] = packbf2(sacc[s][0], sacc[s][1]);
            pw1[s] = packbf2(sacc[s][2], sacc[s][3]);
        }

        // ---- O += P V via 16x16x16 (A-frag lane-local: no LDS, no shuffle)
        #pragma unroll
        for (int s = 0; s < 4; ++s) {
            short4v pa;
            { unsigned u2[2] = {pw0[s], pw1[s]}; __builtin_memcpy(&pa, u2, 8); }
            #pragma unroll
            for (int nt = 0; nt < 4; ++nt) {
                short4v vb = *(const short4v*)&VTS[bit][nt * 16 + m][s * 16 + g * 4];
                o[nt] = __builtin_amdgcn_mfma_f32_16x16x16bf16_1k(pa, vb, o[nt], 0, 0, 0);
            }
        }
    }

    // ---- final reduce of l across the 4 g-groups (q = m), write partial
    {
        float ts = lrun;
        ts += __shfl_xor(ts, 16, 64);
        ts += __shfl_xor(ts, 32, 64);
        if (lane < 16) lp[sidx * 64 + w * 16 + m] = ts;
    }
    #pragma unroll
    for (int nt = 0; nt < 4; ++nt)
        #pragma unroll
        for (int r = 0; r < 4; ++r)
            op[(size_t)sidx * 4096 + (w * 16 + g * 4 + r) * 64 + nt * 16 + m]
                = f2bf(o[nt][r]);
}

// ---------------------------------------------------------------------------
// Attention phase 2: plain sum-merge of 4 parity partials. Grid 256.
__global__ __launch_bounds__(256)
void attn_merge(const float* __restrict__ lp, const ushort_t* __restrict__ op,
                float* __restrict__ out)
{
    const int bq    = blockIdx.x;
    const int batch = bq >> 5;
    const int tile  = bq & 31;
    const int s0    = (batch * 32 + tile) * 4;

    const int t   = threadIdx.x;
    const int row = t >> 2;
    const int c16 = (t & 3) * 16;

    float l = 0.f;
    #pragma unroll
    for (int p = 0; p < 4; ++p) l += lp[(s0 + p) * 64 + row];
    const float inv = 1.f / l;

    float acc[16];
    #pragma unroll
    for (int j = 0; j < 16; ++j) acc[j] = 0.f;
    #pragma unroll
    for (int p = 0; p < 4; ++p) {
        short8 a0 = *(const short8*)(op + (size_t)(s0 + p) * 4096 + row * 64 + c16);
        short8 a1 = *(const short8*)(op + (size_t)(s0 + p) * 4096 + row * 64 + c16 + 8);
        #pragma unroll
        for (int j = 0; j < 8; ++j) {
            acc[j]     += bf2f((ushort_t)a0[j]);
            acc[j + 8] += bf2f((ushort_t)a1[j]);
        }
    }
    float* dst = out + (size_t)(batch * S + tile * 64 + row) * Hd + c16;
    #pragma unroll
    for (int j = 0; j < 16; ++j) dst[j] = acc[j] * inv;
}

// ---------------------------------------------------------------------------
extern "C" void kernel_launch(void* const* d_in, const int* in_sizes, int n_in,
                              void* d_out, int out_size, void* d_ws, size_t ws_size,
                              hipStream_t stream) {
    const float* x  = (const float*)d_in[0];
    const float* Wk = (const float*)d_in[1];
    const float* Wq = (const float*)d_in[2];
    const float* Wv = (const float*)d_in[3];
    float* out = (float*)d_out;

    ushort_t* qws  = (ushort_t*)d_ws;                      // 16384*64 bf16
    ushort_t* kws  = qws + (size_t)ROWS * Hd;
    ushort_t* vTws = kws + (size_t)ROWS * Hd;              // [8][64][2048] bf16
    ushort_t* WT   = vTws + (size_t)ROWS * Hd;             // 192*1024 bf16
    float*    lpp  = (float*)(WT + (size_t)NTOT * E);      // 1024*64 f32
    ushort_t* opp  = (ushort_t*)(lpp + 1024 * 64);         // 1024*4096 bf16

    prep_wt<<<(NTOT * E) / 256, 256, 0, stream>>>(Wk, Wq, Wv, WT);
    proj_v7<<<ROWS / 32, 256, 0, stream>>>(x, WT, qws, kws, vTws);
    attn_part<<<1024, 256, 0, stream>>>(qws, kws, vTws, lpp, opp);
    attn_merge<<<256, 256, 0, stream>>>(lpp, opp, out);
}